// Round 1
// baseline (333.773 us; speedup 1.0000x reference)
//
#include <hip/hip_runtime.h>
#include <math.h>

#define N_NODES 2000
#define N_EDGES 32000
#define BB 16
#define TT 20
#define NG (BB*TT)      // 320 graphs
#define OUTF 8
#define HID 24
#define FC_OUTD 160
#define FCC_OUTD 20

__device__ __forceinline__ unsigned f2u_mono(float f) {
    unsigned u = __float_as_uint(f);
    return (u & 0x80000000u) ? ~u : (u | 0x80000000u);
}
__device__ __forceinline__ float u2f_mono(unsigned u) {
    return (u & 0x80000000u) ? __uint_as_float(u & 0x7FFFFFFFu)
                             : __uint_as_float(~u);
}

// One block per graph. Computes pooled GAT feature [OUTF] per graph.
__global__ __launch_bounds__(512) void gat_kernel(
    const float* __restrict__ x, const float* __restrict__ edge_w,
    const int* __restrict__ src, const int* __restrict__ dst,
    const float* __restrict__ W_node, const float* __restrict__ W_edge,
    const float* __restrict__ attn_l, const float* __restrict__ attn_e,
    const float* __restrict__ attn_r, const float* __restrict__ gat_b,
    float* __restrict__ feats)
{
    __shared__ float    xs[N_NODES];
    __shared__ unsigned emax_u[N_NODES];
    __shared__ float    den[N_NODES];
    __shared__ float    t1s[N_NODES];
    __shared__ float    t2s[N_NODES];
    __shared__ double   wred1[8], wred2[8];

    const int g   = blockIdx.x;
    const int tid = threadIdx.x;
    const int bs  = blockDim.x;

    // scalar attention coefficients (rank-1 projections collapse)
    float cl = 0.f, ce = 0.f, cr = 0.f;
#pragma unroll
    for (int k = 0; k < OUTF; ++k) {
        cl += W_node[k] * attn_l[k];
        cr += W_node[k] * attn_r[k];
        ce += W_edge[k] * attn_e[k];
    }

    const float* xg = x + (size_t)g * N_NODES;
    const float* wg = edge_w + (size_t)g * N_EDGES;

    for (int n = tid; n < N_NODES; n += bs) {
        xs[n]     = xg[n];
        emax_u[n] = f2u_mono(-INFINITY);
        den[n]    = 0.f;
        t1s[n]    = 0.f;
        t2s[n]    = 0.f;
    }
    __syncthreads();

    // Pass A: segment max of leaky_relu logits over dst
    for (int e = tid; e < N_EDGES; e += bs) {
        int s = src[e], d = dst[e];
        float w  = wg[e];
        float ev = cl * xs[s] + ce * w + cr * xs[d];
        ev = (ev >= 0.f) ? ev : 0.2f * ev;
        atomicMax(&emax_u[d], f2u_mono(ev));
    }
    __syncthreads();

    // Pass B: accumulate den, T1 = sum num*x[src], T2 = sum num*w per dst
    for (int e = tid; e < N_EDGES; e += bs) {
        int s = src[e], d = dst[e];
        float w  = wg[e];
        float ev = cl * xs[s] + ce * w + cr * xs[d];
        ev = (ev >= 0.f) ? ev : 0.2f * ev;
        float m   = u2f_mono(emax_u[d]);
        float num = expf(ev - m);
        atomicAdd(&den[d], num);
        atomicAdd(&t1s[d], num * xs[s]);
        atomicAdd(&t2s[d], num * w);
    }
    __syncthreads();

    // Node pass: S1 = sum_n T1/den, S2 = sum_n T2/den (skip empty segments)
    double s1 = 0.0, s2 = 0.0;
    for (int n = tid; n < N_NODES; n += bs) {
        float dn = den[n];
        if (dn > 0.f) {
            s1 += (double)(t1s[n] / dn);
            s2 += (double)(t2s[n] / dn);
        }
    }
#pragma unroll
    for (int off = 32; off > 0; off >>= 1) {
        s1 += __shfl_down(s1, off, 64);
        s2 += __shfl_down(s2, off, 64);
    }
    int wave = tid >> 6, lane = tid & 63;
    if (lane == 0) { wred1[wave] = s1; wred2[wave] = s2; }
    __syncthreads();
    if (tid == 0) {
        double a = 0.0, b = 0.0;
        int nw = bs >> 6;
        for (int wv = 0; wv < nw; ++wv) { a += wred1[wv]; b += wred2[wv]; }
        for (int k = 0; k < OUTF; ++k) {
            feats[g * OUTF + k] = gat_b[k] +
                (float)((a * (double)W_node[k] + b * (double)W_edge[k]) / (double)N_NODES);
        }
    }
}

// Single block: LSTM over T=20 steps + fused fc->fcc projection.
__global__ __launch_bounds__(512) void head_kernel(
    const float* __restrict__ feats,
    const float* __restrict__ w_ih, const float* __restrict__ w_hh,
    const float* __restrict__ b_ih, const float* __restrict__ b_hh,
    const float* __restrict__ fc_w, const float* __restrict__ fc_b,
    const float* __restrict__ fcc_w, const float* __restrict__ fcc_b,
    float* __restrict__ out)
{
    __shared__ float s_wih[96 * 8];
    __shared__ float s_whh[96 * HID];
    __shared__ float s_bias[96];
    __shared__ float s_h[BB * HID];
    __shared__ float s_c[BB * HID];
    __shared__ float s_g[BB * 96];
    __shared__ float s_hs[NG * HID];          // 30 KB: all hidden states
    __shared__ float s_M[FCC_OUTD * HID];     // combined fcc_w @ fc_w
    __shared__ float s_b2[FCC_OUTD];

    const int tid = threadIdx.x, bs = blockDim.x;

    for (int i = tid; i < 96 * 8;   i += bs) s_wih[i] = w_ih[i];
    for (int i = tid; i < 96 * HID; i += bs) s_whh[i] = w_hh[i];
    for (int i = tid; i < 96;       i += bs) s_bias[i] = b_ih[i] + b_hh[i];
    for (int i = tid; i < BB * HID; i += bs) { s_h[i] = 0.f; s_c[i] = 0.f; }

    // combined projection: M[j][h] = sum_m fcc_w[j][m] * fc_w[m][h]
    for (int u = tid; u < FCC_OUTD * HID; u += bs) {
        int j = u / HID, h = u % HID;
        float acc = 0.f;
        for (int m = 0; m < FC_OUTD; ++m) acc += fcc_w[j * FC_OUTD + m] * fc_w[m * HID + h];
        s_M[u] = acc;
    }
    for (int j = tid; j < FCC_OUTD; j += bs) {
        float acc = fcc_b[j];
        for (int m = 0; m < FC_OUTD; ++m) acc += fcc_w[j * FC_OUTD + m] * fc_b[m];
        s_b2[j] = acc;
    }
    __syncthreads();

    for (int t = 0; t < TT; ++t) {
        // gates: 16 batches x 96 units, dot over 8 (input) + 24 (hidden)
        for (int u = tid; u < BB * 96; u += bs) {
            int b = u / 96, j = u % 96;
            float acc = s_bias[j];
            const float* xt = &feats[(b * TT + t) * OUTF];
#pragma unroll
            for (int k = 0; k < OUTF; ++k) acc += xt[k] * s_wih[j * OUTF + k];
            const float* hb = &s_h[b * HID];
#pragma unroll
            for (int k = 0; k < HID; ++k) acc += hb[k] * s_whh[j * HID + k];
            s_g[u] = acc;
        }
        __syncthreads();
        for (int u = tid; u < BB * HID; u += bs) {
            int b = u / HID, j = u % HID;
            float gi = s_g[b * 96 + j];
            float gf = s_g[b * 96 + 24 + j];
            float gg = s_g[b * 96 + 48 + j];
            float go = s_g[b * 96 + 72 + j];
            float i_ = 1.f / (1.f + expf(-gi));
            float f_ = 1.f / (1.f + expf(-gf));
            float g_ = tanhf(gg);
            float o_ = 1.f / (1.f + expf(-go));
            float c = f_ * s_c[u] + i_ * g_;
            s_c[u] = c;
            float h = o_ * tanhf(c);
            s_h[u] = h;
            s_hs[(b * TT + t) * HID + j] = h;
        }
        __syncthreads();
    }

    // out[r][j] = b2[j] + sum_h hs[r][h] * M[j][h]   (320 x 20)
    for (int u = tid; u < NG * FCC_OUTD; u += bs) {
        int r = u / FCC_OUTD, j = u % FCC_OUTD;
        float acc = s_b2[j];
        const float* hr = &s_hs[r * HID];
#pragma unroll
        for (int h = 0; h < HID; ++h) acc += hr[h] * s_M[j * HID + h];
        out[u] = acc;
    }
}

extern "C" void kernel_launch(void* const* d_in, const int* in_sizes, int n_in,
                              void* d_out, int out_size, void* d_ws, size_t ws_size,
                              hipStream_t stream) {
    const float* x      = (const float*)d_in[0];
    const float* edge_w = (const float*)d_in[1];
    const int*   src    = (const int*)d_in[2];
    const int*   dst    = (const int*)d_in[3];
    const float* W_node = (const float*)d_in[4];
    const float* W_edge = (const float*)d_in[5];
    const float* attn_l = (const float*)d_in[6];
    const float* attn_e = (const float*)d_in[7];
    const float* attn_r = (const float*)d_in[8];
    const float* gat_b  = (const float*)d_in[9];
    const float* w_ih   = (const float*)d_in[10];
    const float* w_hh   = (const float*)d_in[11];
    const float* b_ih   = (const float*)d_in[12];
    const float* b_hh   = (const float*)d_in[13];
    const float* fc_w   = (const float*)d_in[14];
    const float* fc_b   = (const float*)d_in[15];
    const float* fcc_w  = (const float*)d_in[16];
    const float* fcc_b  = (const float*)d_in[17];

    float* feats = (float*)d_ws;           // [NG][OUTF] = 10 KB
    float* out   = (float*)d_out;          // [NG][FCC_OUTD]

    gat_kernel<<<NG, 512, 0, stream>>>(x, edge_w, src, dst, W_node, W_edge,
                                       attn_l, attn_e, attn_r, gat_b, feats);
    head_kernel<<<1, 512, 0, stream>>>(feats, w_ih, w_hh, b_ih, b_hh,
                                       fc_w, fc_b, fcc_w, fcc_b, out);
}

// Round 2
// 173.957 us; speedup vs baseline: 1.9187x; 1.9187x over previous
//
#include <hip/hip_runtime.h>
#include <math.h>

#define N_NODES 2000
#define N_EDGES 32000
#define BB 16
#define TT 20
#define NG (BB*TT)      // 320 graphs
#define OUTF 8
#define HID 24
#define FC_OUTD 160
#define FCC_OUTD 20
#define SLICES 8
#define NPS (N_NODES/SLICES)   // 250 nodes per slice

// ---------- CSR build (per-launch, deterministic up to fp-atomic-free int ops) ----------

__global__ void hist_kernel(const int* __restrict__ dst, int* __restrict__ counts) {
    int e = blockIdx.x * blockDim.x + threadIdx.x;
    if (e < N_EDGES) atomicAdd(&counts[dst[e]], 1);
}

__global__ __launch_bounds__(1024) void scan_kernel(const int* __restrict__ counts,
                                                    int* __restrict__ row_ptr) {
    __shared__ int a[2048], b[2048];
    int tid = threadIdx.x;
    for (int i = tid; i < 2048; i += 1024) a[i] = (i < N_NODES) ? counts[i] : 0;
    __syncthreads();
    int* s = a; int* d = b;
    for (int off = 1; off < 2048; off <<= 1) {
        for (int i = tid; i < 2048; i += 1024)
            d[i] = s[i] + (i >= off ? s[i - off] : 0);
        __syncthreads();
        int* t = s; s = d; d = t;
    }
    for (int i = tid; i < N_NODES; i += 1024) row_ptr[i + 1] = s[i];  // inclusive -> row_ptr
    if (tid == 0) row_ptr[0] = 0;
}

__global__ void scatter_kernel(const int* __restrict__ src, const int* __restrict__ dst,
                               const int* __restrict__ row_ptr, int* __restrict__ cursor,
                               unsigned* __restrict__ csr_pack) {
    int e = blockIdx.x * blockDim.x + threadIdx.x;
    if (e < N_EDGES) {
        int d = dst[e];
        int pos = row_ptr[d] + atomicAdd(&cursor[d], 1);
        csr_pack[pos] = ((unsigned)e << 11) | (unsigned)src[e];   // src < 2048
    }
}

// ---------- main GAT: atomic-free per-(graph,node) softmax, single pass ----------

__global__ __launch_bounds__(256) void gat_main(
    const float* __restrict__ x, const float* __restrict__ edge_w,
    const int* __restrict__ row_ptr, const unsigned* __restrict__ csr_pack,
    const float* __restrict__ W_node, const float* __restrict__ W_edge,
    const float* __restrict__ attn_l, const float* __restrict__ attn_e,
    const float* __restrict__ attn_r,
    double* __restrict__ partials)
{
    __shared__ float xs[N_NODES];
    __shared__ double wr1[4], wr2[4];

    const int b   = blockIdx.x;
    const int g   = b % NG;       // slice-major: all 8 slices of g share b%8 -> same XCD
    const int sl  = b / NG;
    const int tid = threadIdx.x;

    float cl = 0.f, ce = 0.f, cr = 0.f;
#pragma unroll
    for (int k = 0; k < OUTF; ++k) {
        cl += W_node[k] * attn_l[k];
        cr += W_node[k] * attn_r[k];
        ce += W_edge[k] * attn_e[k];
    }

    const float* xg = x + (size_t)g * N_NODES;
    const float* wg = edge_w + (size_t)g * N_EDGES;

    for (int n = tid; n < N_NODES; n += 256) xs[n] = xg[n];
    __syncthreads();

    double s1 = 0.0, s2 = 0.0;
    const int n0 = sl * NPS;
    for (int n = n0 + tid; n < n0 + NPS; n += 256) {
        int p0 = row_ptr[n], p1 = row_ptr[n + 1];
        float den = 0.f, t1 = 0.f, t2 = 0.f;
        float xd = xs[n];
        for (int p = p0; p < p1; ++p) {
            unsigned pk = csr_pack[p];
            int s   = pk & 2047u;
            int eid = pk >> 11;
            float w   = wg[eid];
            float xsv = xs[s];
            float ev  = cl * xsv + ce * w + cr * xd;
            ev = (ev >= 0.f) ? ev : 0.2f * ev;
            float num = expf(ev);       // max-shift dropped: ratio-invariant, |ev| ~< 1
            den += num;
            t1  += num * xsv;
            t2  += num * w;
        }
        if (den > 0.f) { s1 += (double)(t1 / den); s2 += (double)(t2 / den); }
    }

#pragma unroll
    for (int off = 32; off > 0; off >>= 1) {
        s1 += __shfl_down(s1, off, 64);
        s2 += __shfl_down(s2, off, 64);
    }
    int wave = tid >> 6, lane = tid & 63;
    if (lane == 0) { wr1[wave] = s1; wr2[wave] = s2; }
    __syncthreads();
    if (tid == 0) {
        double a = 0.0, c = 0.0;
        for (int w = 0; w < 4; ++w) { a += wr1[w]; c += wr2[w]; }
        partials[(size_t)b * 2 + 0] = a;
        partials[(size_t)b * 2 + 1] = c;
    }
}

__global__ void feats_kernel(const double* __restrict__ partials,
                             const float* __restrict__ W_node, const float* __restrict__ W_edge,
                             const float* __restrict__ gat_b, float* __restrict__ feats) {
    int g = blockIdx.x * blockDim.x + threadIdx.x;
    if (g < NG) {
        double a = 0.0, c = 0.0;
        for (int s = 0; s < SLICES; ++s) {
            a += partials[(size_t)(s * NG + g) * 2 + 0];
            c += partials[(size_t)(s * NG + g) * 2 + 1];
        }
#pragma unroll
        for (int k = 0; k < OUTF; ++k)
            feats[g * OUTF + k] = gat_b[k] +
                (float)((a * (double)W_node[k] + c * (double)W_edge[k]) / (double)N_NODES);
    }
}

// ---------- LSTM + fused fc->fcc head ----------

__global__ __launch_bounds__(512) void head_kernel(
    const float* __restrict__ feats,
    const float* __restrict__ w_ih, const float* __restrict__ w_hh,
    const float* __restrict__ b_ih, const float* __restrict__ b_hh,
    const float* __restrict__ fc_w, const float* __restrict__ fc_b,
    const float* __restrict__ fcc_w, const float* __restrict__ fcc_b,
    float* __restrict__ out)
{
    __shared__ float s_f[NG * OUTF];          // 10 KB: all GAT features
    __shared__ float s_wih[96 * 8];
    __shared__ float s_whh[96 * HID];
    __shared__ float s_bias[96];
    __shared__ float s_h[BB * HID];
    __shared__ float s_c[BB * HID];
    __shared__ float s_g[BB * 96];
    __shared__ float s_hs[NG * HID];          // 30 KB: all hidden states
    __shared__ float s_M[FCC_OUTD * HID];     // combined fcc_w @ fc_w
    __shared__ float s_b2[FCC_OUTD];

    const int tid = threadIdx.x, bs = blockDim.x;

    for (int i = tid; i < NG * OUTF; i += bs) s_f[i] = feats[i];
    for (int i = tid; i < 96 * 8;    i += bs) s_wih[i] = w_ih[i];
    for (int i = tid; i < 96 * HID;  i += bs) s_whh[i] = w_hh[i];
    for (int i = tid; i < 96;        i += bs) s_bias[i] = b_ih[i] + b_hh[i];
    for (int i = tid; i < BB * HID;  i += bs) { s_h[i] = 0.f; s_c[i] = 0.f; }

    // combined projection: M[j][h] = sum_m fcc_w[j][m] * fc_w[m][h]
    for (int u = tid; u < FCC_OUTD * HID; u += bs) {
        int j = u / HID, h = u % HID;
        float acc = 0.f;
        for (int m = 0; m < FC_OUTD; ++m) acc += fcc_w[j * FC_OUTD + m] * fc_w[m * HID + h];
        s_M[u] = acc;
    }
    for (int j = tid; j < FCC_OUTD; j += bs) {
        float acc = fcc_b[j];
        for (int m = 0; m < FC_OUTD; ++m) acc += fcc_w[j * FC_OUTD + m] * fc_b[m];
        s_b2[j] = acc;
    }
    __syncthreads();

    for (int t = 0; t < TT; ++t) {
        for (int u = tid; u < BB * 96; u += bs) {
            int b = u / 96, j = u % 96;
            float acc = s_bias[j];
            const float* xt = &s_f[(b * TT + t) * OUTF];
#pragma unroll
            for (int k = 0; k < OUTF; ++k) acc += xt[k] * s_wih[j * OUTF + k];
            const float* hb = &s_h[b * HID];
#pragma unroll
            for (int k = 0; k < HID; ++k) acc += hb[k] * s_whh[j * HID + k];
            s_g[u] = acc;
        }
        __syncthreads();
        for (int u = tid; u < BB * HID; u += bs) {
            int b = u / HID, j = u % HID;
            float gi = s_g[b * 96 + j];
            float gf = s_g[b * 96 + 24 + j];
            float gg = s_g[b * 96 + 48 + j];
            float go = s_g[b * 96 + 72 + j];
            float i_ = 1.f / (1.f + expf(-gi));
            float f_ = 1.f / (1.f + expf(-gf));
            float g_ = tanhf(gg);
            float o_ = 1.f / (1.f + expf(-go));
            float c = f_ * s_c[u] + i_ * g_;
            s_c[u] = c;
            float h = o_ * tanhf(c);
            s_h[u] = h;
            s_hs[(b * TT + t) * HID + j] = h;
        }
        __syncthreads();
    }

    for (int u = tid; u < NG * FCC_OUTD; u += bs) {
        int r = u / FCC_OUTD, j = u % FCC_OUTD;
        float acc = s_b2[j];
        const float* hr = &s_hs[r * HID];
#pragma unroll
        for (int h = 0; h < HID; ++h) acc += hr[h] * s_M[j * HID + h];
        out[u] = acc;
    }
}

extern "C" void kernel_launch(void* const* d_in, const int* in_sizes, int n_in,
                              void* d_out, int out_size, void* d_ws, size_t ws_size,
                              hipStream_t stream) {
    const float* x      = (const float*)d_in[0];
    const float* edge_w = (const float*)d_in[1];
    const int*   src    = (const int*)d_in[2];
    const int*   dst    = (const int*)d_in[3];
    const float* W_node = (const float*)d_in[4];
    const float* W_edge = (const float*)d_in[5];
    const float* attn_l = (const float*)d_in[6];
    const float* attn_e = (const float*)d_in[7];
    const float* attn_r = (const float*)d_in[8];
    const float* gat_b  = (const float*)d_in[9];
    const float* w_ih   = (const float*)d_in[10];
    const float* w_hh   = (const float*)d_in[11];
    const float* b_ih   = (const float*)d_in[12];
    const float* b_hh   = (const float*)d_in[13];
    const float* fc_w   = (const float*)d_in[14];
    const float* fc_b   = (const float*)d_in[15];
    const float* fcc_w  = (const float*)d_in[16];
    const float* fcc_b  = (const float*)d_in[17];

    char* ws = (char*)d_ws;
    int*      counts   = (int*)(ws + 0);            // 8000 B (also reused as cursor)
    int*      row_ptr  = (int*)(ws + 8192);         // 8004 B
    unsigned* csr_pack = (unsigned*)(ws + 16384);   // 128000 B
    double*   partials = (double*)(ws + 147456);    // 2560*2*8 = 40960 B
    float*    feats    = (float*)(ws + 188416);     // 10240 B
    float*    out      = (float*)d_out;

    hipMemsetAsync(counts, 0, N_NODES * sizeof(int), stream);
    hist_kernel<<<(N_EDGES + 255) / 256, 256, 0, stream>>>(dst, counts);
    scan_kernel<<<1, 1024, 0, stream>>>(counts, row_ptr);
    hipMemsetAsync(counts, 0, N_NODES * sizeof(int), stream);
    scatter_kernel<<<(N_EDGES + 255) / 256, 256, 0, stream>>>(src, dst, row_ptr, counts, csr_pack);

    gat_main<<<NG * SLICES, 256, 0, stream>>>(x, edge_w, row_ptr, csr_pack,
                                              W_node, W_edge, attn_l, attn_e, attn_r, partials);
    feats_kernel<<<(NG + 255) / 256, 256, 0, stream>>>(partials, W_node, W_edge, gat_b, feats);
    head_kernel<<<1, 512, 0, stream>>>(feats, w_ih, w_hh, b_ih, b_hh,
                                       fc_w, fc_b, fcc_w, fcc_b, out);
}